// Round 3
// baseline (1654.711 us; speedup 1.0000x reference)
//
#include <hip/hip_runtime.h>
#include <math.h>

#define BDIM 2
#define CDIM 256
#define HDIM 128
#define WDIM 128
#define HW (HDIM*WDIM)
#define NPIX (BDIM*HW)

typedef float f32x4 __attribute__((ext_vector_type(4)));
typedef short bf16x8 __attribute__((ext_vector_type(8)));
typedef short bf16x4 __attribute__((ext_vector_type(4)));

__device__ __forceinline__ float geluf(float x){
  return 0.5f*x*(1.f+erff(x*0.70710678118654752f));
}
__device__ __forceinline__ unsigned short f2bf(float f){
  union{float f;unsigned u;}v; v.f=f;
  unsigned r=(v.u + 0x7FFFu + ((v.u>>16)&1u))>>16; return (unsigned short)r;
}
__device__ __forceinline__ float bf2f(unsigned short h){
  union{unsigned u;float f;}v; v.u=((unsigned)h)<<16; return v.f;
}

// ---------------- NCHW fp32 -> NHWC bf16 ----------------
__global__ __launch_bounds__(256) void k_transpose(const float* __restrict__ in,
                                                   unsigned short* __restrict__ out){
  __shared__ float tile[32][33];
  int b = blockIdx.z;
  int c0 = blockIdx.y*32;
  int p0 = blockIdx.x*32;
  int tx = threadIdx.x, ty = threadIdx.y;
  const float* src = in + (size_t)b*CDIM*HW;
  unsigned short* dst = out + (size_t)b*HW*CDIM;
  #pragma unroll
  for (int i=ty;i<32;i+=8) tile[i][tx] = src[(size_t)(c0+i)*HW + p0+tx];
  __syncthreads();
  #pragma unroll
  for (int i=ty;i<32;i+=8) dst[(size_t)(p0+i)*CDIM + c0+tx] = f2bf(tile[tx][i]);
}

// ---------------- weight packers: fragment-linear bf16 ----------------
__global__ void k_pack_w(const float* __restrict__ src, unsigned short* __restrict__ dst,
                         int ksn, int K, int total){
  for (int i=blockIdx.x*256+threadIdx.x; i<total; i+=gridDim.x*256){
    int r=i&7, l=(i>>3)&63, ks=(i>>9)%ksn, J=i/(ksn*512);
    int j=J*16+(l&15), k=ks*32+((l>>4)<<3)+r;
    dst[i]=f2bf(src[(size_t)j*K+k]);
  }
}
__global__ void k_pack_off(const float* __restrict__ src, unsigned short* __restrict__ dst){
  const int total=2*72*512;
  for (int i=blockIdx.x*256+threadIdx.x; i<total; i+=gridDim.x*256){
    int r=i&7, l=(i>>3)&63, ks=(i>>9)%72, J=i/(72*512);
    int oc=J*16+(l&15), k=ks*32+((l>>4)<<3)+r;
    int tap=k>>8, ch=k&255;
    float v = (oc<18) ? src[((size_t)(oc*256+ch)*3 + tap/3)*3 + (tap%3)] : 0.f;
    dst[i]=f2bf(v);
  }
}
// depthwise weights -> [branch][tap][ch] fp32
__global__ void k_pack_dwt(const float* __restrict__ s0, const float* __restrict__ s1,
                           const float* __restrict__ s2, float* __restrict__ dst){
  int i = blockIdx.x*256+threadIdx.x;
  if (i < 3*9*256){
    int j=i/2304, rem=i%2304, k=rem/256, c=rem%256;
    const float* s = j==0?s0:(j==1?s1:s2);
    dst[i] = s[c*9+k];
  }
}

// ---------------- offset conv via MFMA: D[oc][pix] = Woff . T^T ----------------
// writes off[pix*54 + oc] (base pre-offset by branch*18)
template<int DIL>
__global__ __launch_bounds__(256) void k_offconv(const unsigned short* __restrict__ xtb,
    const unsigned short* __restrict__ wp, float* __restrict__ off){
  __shared__ float part[4*2*2*64*4];   // 16KB
  int t=threadIdx.x, l=t&63, wv=t>>6, q=l>>4;
  int p0=blockIdx.x*32;
  int b=p0>>14, prow=p0&(HW-1);
  int hh=prow>>7, w0=prow&(WDIM-1);
  const unsigned short* xb = xtb + (size_t)b*HW*CDIM;
  f32x4 acc[2][2];
  #pragma unroll
  for(int mi=0;mi<2;mi++)
    #pragma unroll
    for(int pi=0;pi<2;pi++) acc[mi][pi]=(f32x4){0.f,0.f,0.f,0.f};
  for(int i=0;i<18;i++){
    int ks = wv + 4*i;
    int k0 = ks*32;
    int tap = k0>>8;
    int ky = tap/3, kx = tap%3;
    int chb = (k0&255) + q*8;
    bf16x8 a0 = *(const bf16x8*)(wp + ((size_t)(0*72+ks)*64 + l)*8);
    bf16x8 a1 = *(const bf16x8*)(wp + ((size_t)(1*72+ks)*64 + l)*8);
    int y = hh + (ky-1)*DIL;
    bf16x8 bfr[2];
    #pragma unroll
    for(int pi=0;pi<2;pi++){
      int x = w0 + pi*16 + (l&15) + (kx-1)*DIL;
      bf16x8 v = {0,0,0,0,0,0,0,0};
      if((unsigned)y<HDIM && (unsigned)x<WDIM)
        v = *(const bf16x8*)(xb + ((size_t)y*WDIM + x)*CDIM + chb);
      bfr[pi]=v;
    }
    #pragma unroll
    for(int pi=0;pi<2;pi++){
      acc[0][pi]=__builtin_amdgcn_mfma_f32_16x16x32_bf16(a0,bfr[pi],acc[0][pi],0,0,0);
      acc[1][pi]=__builtin_amdgcn_mfma_f32_16x16x32_bf16(a1,bfr[pi],acc[1][pi],0,0,0);
    }
  }
  #pragma unroll
  for(int mi=0;mi<2;mi++)
    #pragma unroll
    for(int pi=0;pi<2;pi++){
      float* pp = &part[(((wv*2+mi)*2+pi)*64 + l)*4];
      pp[0]=acc[mi][pi].x; pp[1]=acc[mi][pi].y; pp[2]=acc[mi][pi].z; pp[3]=acc[mi][pi].w;
    }
  __syncthreads();
  if(wv==0){
    #pragma unroll
    for(int mi=0;mi<2;mi++)
      #pragma unroll
      for(int pi=0;pi<2;pi++)
        #pragma unroll
        for(int r=0;r<4;r++){
          int oc = mi*16 + q*4 + r;
          if(oc<18){
            float s=0.f;
            #pragma unroll
            for(int ww=0;ww<4;ww++) s += part[(((ww*2+mi)*2+pi)*64+l)*4 + r];
            off[(size_t)(p0 + pi*16 + (l&15))*54 + oc] = s;
          }
        }
  }
}

// ---------------- 1x1 conv via MFMA: acc[pix][oc] = conv_w . x^T + b ----------------
__global__ __launch_bounds__(256) void k_conv1x1(const unsigned short* __restrict__ xtb,
    const unsigned short* __restrict__ cwp, const float* __restrict__ cb,
    float* __restrict__ acc){
  __shared__ float sacc[32*260];
  int t=threadIdx.x, l=t&63, wv=t>>6, q=l>>4;
  size_t p0=(size_t)blockIdx.x*32;
  f32x4 c[4][2];
  #pragma unroll
  for(int ci=0;ci<4;ci++)
    #pragma unroll
    for(int pi=0;pi<2;pi++) c[ci][pi]=(f32x4){0.f,0.f,0.f,0.f};
  for(int ks=0;ks<8;ks++){
    bf16x8 bfr[2];
    #pragma unroll
    for(int pi=0;pi<2;pi++)
      bfr[pi] = *(const bf16x8*)(xtb + (p0 + pi*16 + (l&15))*CDIM + ks*32 + q*8);
    #pragma unroll
    for(int ci=0;ci<4;ci++){
      int J = wv*4+ci;
      bf16x8 a = *(const bf16x8*)(cwp + ((size_t)(J*8+ks)*64+l)*8);
      #pragma unroll
      for(int pi=0;pi<2;pi++)
        c[ci][pi]=__builtin_amdgcn_mfma_f32_16x16x32_bf16(a,bfr[pi],c[ci][pi],0,0,0);
    }
  }
  #pragma unroll
  for(int ci=0;ci<4;ci++){
    int ocb = (wv*4+ci)*16 + q*4;
    float4 bb = *(const float4*)&cb[ocb];
    #pragma unroll
    for(int pi=0;pi<2;pi++){
      int pix = pi*16+(l&15);
      sacc[pix*260 + ocb+0] = c[ci][pi].x + bb.x;
      sacc[pix*260 + ocb+1] = c[ci][pi].y + bb.y;
      sacc[pix*260 + ocb+2] = c[ci][pi].z + bb.z;
      sacc[pix*260 + ocb+3] = c[ci][pi].w + bb.w;
    }
  }
  __syncthreads();
  for(int i=0;i<32;i++) acc[(p0+i)*CDIM + t] = sacc[i*260 + t];
}

// ------- fused 3-branch deformable depthwise 3x3 + LN + GELU, acc += ... -------
// one pixel per wave; lane = (x-corner h=l>>5, channel octet c0=(l&31)*8)
__global__ __launch_bounds__(256) void k_deform3(const unsigned short* __restrict__ xtb,
    const float* __restrict__ offall, const float* __restrict__ wkt,
    const float* __restrict__ lw0, const float* __restrict__ lb0,
    const float* __restrict__ lw1, const float* __restrict__ lb1,
    const float* __restrict__ lw2, const float* __restrict__ lb2,
    float* __restrict__ acc){
  __shared__ float wsh[3*9*256];   // 27648 B
  int t=threadIdx.x, l=t&63, wv=t>>6;
  for(int i=t;i<3*9*256;i+=256) wsh[i]=wkt[i];
  __syncthreads();
  size_t gp = (size_t)blockIdx.x*4 + wv;
  int b=(int)(gp>>14); int p=(int)(gp&(HW-1)); int hh=p>>7, ww=p&(WDIM-1);
  float voff = 0.f;
  if(l<54) voff = offall[gp*54 + l];
  const unsigned short* xb = xtb + (size_t)b*HW*CDIM;
  const int h = l>>5;           // x-corner
  const int c0 = (l&31)*8;      // channel base
  float d[3][8];
  #pragma unroll
  for(int j=0;j<3;j++)
    #pragma unroll
    for(int e=0;e<8;e++) d[j][e]=0.f;
  const int DILS[3]={1,9,12};
  #pragma unroll
  for(int j=0;j<3;j++){
    const int DIL=DILS[j];
    #pragma unroll
    for(int k=0;k<9;k++){
      float oy = __shfl(voff, j*18+2*k);
      float ox = __shfl(voff, j*18+2*k+1);
      float py = (float)(hh+(k/3-1)*DIL)+oy;
      float px = (float)(ww+(k%3-1)*DIL)+ox;
      float y0f=floorf(py), x0f=floorf(px);
      float fy=py-y0f, fx=px-x0f;
      int iy=(int)y0f, ix=(int)x0f;
      int xx = ix + h;
      float wx = h ? fx : 1.f-fx;
      float v0[8], v1[8];
      #pragma unroll
      for(int e=0;e<8;e++){ v0[e]=0.f; v1[e]=0.f; }
      if((unsigned)xx < WDIM){
        if((unsigned)iy < HDIM){
          bf16x8 r = *(const bf16x8*)(xb + ((size_t)iy*WDIM + xx)*CDIM + c0);
          #pragma unroll
          for(int e=0;e<8;e++) v0[e]=bf2f((unsigned short)r[e]);
        }
        if((unsigned)(iy+1) < HDIM){
          bf16x8 r = *(const bf16x8*)(xb + ((size_t)(iy+1)*WDIM + xx)*CDIM + c0);
          #pragma unroll
          for(int e=0;e<8;e++) v1[e]=bf2f((unsigned short)r[e]);
        }
      }
      float w0 = wx*(1.f-fy), w1 = wx*fy;
      const float* wrow = &wsh[(j*9+k)*256 + c0];
      #pragma unroll
      for(int e=0;e<8;e++)
        d[j][e] = fmaf(wrow[e], fmaf(w1, v1[e], w0*v0[e]), d[j][e]);
    }
  }
  // combine the two x-corner halves (lanes l <-> l+32)
  #pragma unroll
  for(int j=0;j<3;j++)
    #pragma unroll
    for(int e=0;e<8;e++)
      d[j][e] += __shfl_xor(d[j][e], 32);
  // LN + gelu per branch (in-wave reduce; both halves hold identical data)
  float r8[8];
  #pragma unroll
  for(int e=0;e<8;e++) r8[e]=0.f;
  #pragma unroll
  for(int j=0;j<3;j++){
    float s=0.f, sq=0.f;
    #pragma unroll
    for(int e=0;e<8;e++){ s+=d[j][e]; sq+=d[j][e]*d[j][e]; }
    #pragma unroll
    for(int m=1;m<32;m<<=1){ s+=__shfl_xor(s,m); sq+=__shfl_xor(sq,m); }
    float u=s*(1.f/CDIM);
    float var=sq*(1.f/CDIM)-u*u;
    float rs=rsqrtf(var+1e-6f);
    const float* lw = j==0?lw0:(j==1?lw1:lw2);
    const float* lb = j==0?lb0:(j==1?lb1:lb2);
    float4 wA = *(const float4*)&lw[c0];
    float4 wB = *(const float4*)&lw[c0+4];
    float4 bA = *(const float4*)&lb[c0];
    float4 bB = *(const float4*)&lb[c0+4];
    float lwv[8]={wA.x,wA.y,wA.z,wA.w,wB.x,wB.y,wB.z,wB.w};
    float lbv[8]={bA.x,bA.y,bA.z,bA.w,bB.x,bB.y,bB.z,bB.w};
    #pragma unroll
    for(int e=0;e<8;e++)
      r8[e] += geluf(lwv[e]*((d[j][e]-u)*rs)+lbv[e]);
  }
  // accumulate: half 0 writes channels c0..c0+3, half 1 writes c0+4..c0+7
  float4* ap = (float4*)&acc[gp*CDIM + c0 + 4*h];
  float4 av = *ap;
  if(h==0){ av.x+=r8[0]; av.y+=r8[1]; av.z+=r8[2]; av.w+=r8[3]; }
  else    { av.x+=r8[4]; av.y+=r8[5]; av.z+=r8[6]; av.w+=r8[7]; }
  *ap = av;
}

// ------- fused LN1 + MLP(256->512 gelu ->256, MFMA) + residual + LN2 + NCHW -------
__global__ __launch_bounds__(256) void k_mlp(const float* __restrict__ acc,
    const unsigned short* __restrict__ w1p, const float* __restrict__ b1,
    const unsigned short* __restrict__ w2p, const float* __restrict__ b2,
    const float* __restrict__ n1w, const float* __restrict__ n1b,
    const float* __restrict__ n2w, const float* __restrict__ n2b,
    float* __restrict__ dout){
  __shared__ unsigned short xbf[32*256];
  __shared__ unsigned short hbf[32*512];
  __shared__ float redS[4*32], redQ[4*32];
  int t=threadIdx.x, l=t&63, wv=t>>6, q=l>>4;
  size_t p0=(size_t)blockIdx.x*32;
  {
    int p=t>>3, i=t&7;
    const float* ar = acc + (p0+p)*CDIM + i*32;
    float v[32];
    float s=0.f, sq=0.f;
    #pragma unroll
    for(int j=0;j<32;j+=4){
      float4 x4 = *(const float4*)&ar[j];
      v[j]=x4.x; v[j+1]=x4.y; v[j+2]=x4.z; v[j+3]=x4.w;
      s += x4.x+x4.y+x4.z+x4.w;
      sq += x4.x*x4.x+x4.y*x4.y+x4.z*x4.z+x4.w*x4.w;
    }
    #pragma unroll
    for(int m=1;m<8;m<<=1){ s += __shfl_xor(s,m); sq += __shfl_xor(sq,m); }
    float u=s*(1.f/CDIM), var=sq*(1.f/CDIM)-u*u, rs=rsqrtf(var+1e-6f);
    #pragma unroll
    for(int g4=0; g4<4; ++g4){
      bf16x8 vec;
      #pragma unroll
      for(int e=0;e<8;e++){
        int c=i*32+g4*8+e;
        float y=(v[g4*8+e]-u)*rs*n1w[c]+n1b[c];
        vec[e]=(short)f2bf(y);
      }
      int g = i*4 + g4;
      *(bf16x8*)&xbf[p*256 + ((g ^ (p&7))<<3)] = vec;
    }
  }
  __syncthreads();
  f32x4 c1[8][2];
  #pragma unroll
  for(int ji=0;ji<8;ji++){ c1[ji][0]=(f32x4){0.f,0.f,0.f,0.f}; c1[ji][1]=(f32x4){0.f,0.f,0.f,0.f}; }
  for(int ks=0;ks<8;ks++){
    bf16x8 bx[2];
    #pragma unroll
    for(int pi=0;pi<2;pi++){
      int pix=pi*16+(l&15);
      int g=ks*4+q;
      bx[pi]=*(const bf16x8*)&xbf[pix*256 + ((g^(pix&7))<<3)];
    }
    #pragma unroll
    for(int ji=0;ji<8;ji++){
      bf16x8 a=*(const bf16x8*)(w1p + ((size_t)((wv*8+ji)*8+ks)*64+l)*8);
      c1[ji][0]=__builtin_amdgcn_mfma_f32_16x16x32_bf16(a,bx[0],c1[ji][0],0,0,0);
      c1[ji][1]=__builtin_amdgcn_mfma_f32_16x16x32_bf16(a,bx[1],c1[ji][1],0,0,0);
    }
  }
  #pragma unroll
  for(int ji=0;ji<8;ji++){
    int jb=(wv*8+ji)*16 + q*4;
    float4 bb=*(const float4*)&b1[jb];
    #pragma unroll
    for(int pi=0;pi<2;pi++){
      int pix=pi*16+(l&15);
      bf16x4 t4;
      t4[0]=(short)f2bf(geluf(c1[ji][pi].x+bb.x));
      t4[1]=(short)f2bf(geluf(c1[ji][pi].y+bb.y));
      t4[2]=(short)f2bf(geluf(c1[ji][pi].z+bb.z));
      t4[3]=(short)f2bf(geluf(c1[ji][pi].w+bb.w));
      int g=jb>>3;
      *(bf16x4*)&hbf[pix*512 + ((g^(pix&7))<<3) + (jb&7)] = t4;
    }
  }
  __syncthreads();
  f32x4 c2[4][2];
  #pragma unroll
  for(int ci=0;ci<4;ci++){ c2[ci][0]=(f32x4){0.f,0.f,0.f,0.f}; c2[ci][1]=(f32x4){0.f,0.f,0.f,0.f}; }
  for(int ks=0;ks<16;ks++){
    bf16x8 bh[2];
    #pragma unroll
    for(int pi=0;pi<2;pi++){
      int pix=pi*16+(l&15);
      int g=ks*4+q;
      bh[pi]=*(const bf16x8*)&hbf[pix*512 + ((g^(pix&7))<<3)];
    }
    #pragma unroll
    for(int ci=0;ci<4;ci++){
      bf16x8 a=*(const bf16x8*)(w2p + ((size_t)((wv*4+ci)*16+ks)*64+l)*8);
      c2[ci][0]=__builtin_amdgcn_mfma_f32_16x16x32_bf16(a,bh[0],c2[ci][0],0,0,0);
      c2[ci][1]=__builtin_amdgcn_mfma_f32_16x16x32_bf16(a,bh[1],c2[ci][1],0,0,0);
    }
  }
  float z[4][2][4];
  float sp[2]={0.f,0.f}, sqp[2]={0.f,0.f};
  #pragma unroll
  for(int ci=0;ci<4;ci++){
    int cb=(wv*4+ci)*16+q*4;
    float4 bb=*(const float4*)&b2[cb];
    int g=cb>>3;
    #pragma unroll
    for(int pi=0;pi<2;pi++){
      int pix=pi*16+(l&15);
      bf16x4 rr=*(const bf16x4*)&xbf[pix*256 + ((g^(pix&7))<<3) + (cb&7)];
      float z0=c2[ci][pi].x+bb.x+bf2f((unsigned short)rr[0]);
      float z1=c2[ci][pi].y+bb.y+bf2f((unsigned short)rr[1]);
      float z2=c2[ci][pi].z+bb.z+bf2f((unsigned short)rr[2]);
      float z3=c2[ci][pi].w+bb.w+bf2f((unsigned short)rr[3]);
      z[ci][pi][0]=z0; z[ci][pi][1]=z1; z[ci][pi][2]=z2; z[ci][pi][3]=z3;
      sp[pi]+=z0+z1+z2+z3;
      sqp[pi]+=z0*z0+z1*z1+z2*z2+z3*z3;
    }
  }
  #pragma unroll
  for(int m=16;m<64;m<<=1){
    sp[0]+=__shfl_xor(sp[0],m); sp[1]+=__shfl_xor(sp[1],m);
    sqp[0]+=__shfl_xor(sqp[0],m); sqp[1]+=__shfl_xor(sqp[1],m);
  }
  if(q==0){
    redS[wv*32 + (l&15)]=sp[0];  redS[wv*32 + 16 + (l&15)]=sp[1];
    redQ[wv*32 + (l&15)]=sqp[0]; redQ[wv*32 + 16 + (l&15)]=sqp[1];
  }
  __syncthreads();
  float u[2], rs[2];
  #pragma unroll
  for(int pi=0;pi<2;pi++){
    int pix=pi*16+(l&15);
    float S=redS[pix]+redS[32+pix]+redS[64+pix]+redS[96+pix];
    float Q=redQ[pix]+redQ[32+pix]+redQ[64+pix]+redQ[96+pix];
    u[pi]=S*(1.f/CDIM);
    rs[pi]=rsqrtf(Q*(1.f/CDIM)-u[pi]*u[pi]+1e-6f);
  }
  int bimg=(int)(p0>>14); int prow0=(int)(p0&(HW-1));
  #pragma unroll
  for(int ci=0;ci<4;ci++){
    int cb=(wv*4+ci)*16+q*4;
    float4 wv4=*(const float4*)&n2w[cb];
    float4 bv4=*(const float4*)&n2b[cb];
    #pragma unroll
    for(int pi=0;pi<2;pi++){
      int prow = prow0 + pi*16 + (l&15);
      dout[((size_t)(bimg*CDIM+cb+0))*HW + prow] = (z[ci][pi][0]-u[pi])*rs[pi]*wv4.x+bv4.x;
      dout[((size_t)(bimg*CDIM+cb+1))*HW + prow] = (z[ci][pi][1]-u[pi])*rs[pi]*wv4.y+bv4.y;
      dout[((size_t)(bimg*CDIM+cb+2))*HW + prow] = (z[ci][pi][2]-u[pi])*rs[pi]*wv4.z+bv4.z;
      dout[((size_t)(bimg*CDIM+cb+3))*HW + prow] = (z[ci][pi][3]-u[pi])*rs[pi]*wv4.w+bv4.w;
    }
  }
}

extern "C" void kernel_launch(void* const* d_in, const int* in_sizes, int n_in,
                              void* d_out, int out_size, void* d_ws, size_t ws_size,
                              hipStream_t stream){
  const float* x = (const float*)d_in[0];
  const float* off_w[3] = {(const float*)d_in[1],(const float*)d_in[5],(const float*)d_in[9]};
  const float* def_w[3] = {(const float*)d_in[2],(const float*)d_in[6],(const float*)d_in[10]};
  const float* bw[3]    = {(const float*)d_in[3],(const float*)d_in[7],(const float*)d_in[11]};
  const float* bbr[3]   = {(const float*)d_in[4],(const float*)d_in[8],(const float*)d_in[12]};
  const float* conv_w = (const float*)d_in[13];
  const float* conv_b = (const float*)d_in[14];
  const float* n1w = (const float*)d_in[15];
  const float* n1b = (const float*)d_in[16];
  const float* n2w = (const float*)d_in[17];
  const float* n2b = (const float*)d_in[18];
  const float* w1  = (const float*)d_in[19];
  const float* b1  = (const float*)d_in[20];
  const float* w2  = (const float*)d_in[21];
  const float* b2  = (const float*)d_in[22];

  unsigned short* xtb = (unsigned short*)d_ws;                       // NPIX*256 bf16
  float* acc  = (float*)(xtb + (size_t)NPIX*CDIM);                   // NPIX*256 f32
  float* offall = acc + (size_t)NPIX*CDIM;                           // NPIX*54 f32
  unsigned short* w1p  = (unsigned short*)(offall + (size_t)NPIX*54);// 131072
  unsigned short* w2p  = w1p + 131072;                               // 131072
  unsigned short* cwp  = w2p + 131072;                               // 65536
  unsigned short* wop0 = cwp + 65536;                                // 73728 each
  unsigned short* wop1 = wop0 + 73728;
  unsigned short* wop2 = wop1 + 73728;
  float* wkt = (float*)(wop2 + 73728);                               // 6912 f32

  k_transpose<<<dim3(HW/32, CDIM/32, BDIM), dim3(32,8), 0, stream>>>(x, xtb);
  k_pack_w<<<512, 256, 0, stream>>>(w1, w1p, 8, 256, 131072);
  k_pack_w<<<512, 256, 0, stream>>>(w2, w2p, 16, 512, 131072);
  k_pack_w<<<256, 256, 0, stream>>>(conv_w, cwp, 8, 256, 65536);
  k_pack_off<<<288, 256, 0, stream>>>(off_w[0], wop0);
  k_pack_off<<<288, 256, 0, stream>>>(off_w[1], wop1);
  k_pack_off<<<288, 256, 0, stream>>>(off_w[2], wop2);
  k_pack_dwt<<<27, 256, 0, stream>>>(def_w[0], def_w[1], def_w[2], wkt);
  k_offconv<1> <<<NPIX/32, 256, 0, stream>>>(xtb, wop0, offall + 0);
  k_offconv<9> <<<NPIX/32, 256, 0, stream>>>(xtb, wop1, offall + 18);
  k_offconv<12><<<NPIX/32, 256, 0, stream>>>(xtb, wop2, offall + 36);
  k_conv1x1<<<NPIX/32, 256, 0, stream>>>(xtb, cwp, conv_b, acc);
  k_deform3<<<NPIX/4, 256, 0, stream>>>(xtb, offall, wkt,
      bw[0], bbr[0], bw[1], bbr[1], bw[2], bbr[2], acc);
  k_mlp<<<NPIX/32, 256, 0, stream>>>(acc, w1p, b1, w2p, b2, n1w, n1b, n2w, n2b, (float*)d_out);
}

// Round 5
// 301.529 us; speedup vs baseline: 5.4877x; 5.4877x over previous
//
#include <hip/hip_runtime.h>
#include <math.h>

#define BDIM 2
#define CDIM 256
#define HDIM 128
#define WDIM 128
#define HW (HDIM*WDIM)
#define NPIX (BDIM*HW)

typedef float f32x4 __attribute__((ext_vector_type(4)));
typedef short bf16x8 __attribute__((ext_vector_type(8)));
typedef short bf16x4 __attribute__((ext_vector_type(4)));

__device__ __forceinline__ float geluf(float x){
  return 0.5f*x*(1.f+erff(x*0.70710678118654752f));
}
__device__ __forceinline__ unsigned short f2bf(float f){
  union{float f;unsigned u;}v; v.f=f;
  unsigned r=(v.u + 0x7FFFu + ((v.u>>16)&1u))>>16; return (unsigned short)r;
}
__device__ __forceinline__ float bf2f(unsigned short h){
  union{unsigned u;float f;}v; v.u=((unsigned)h)<<16; return v.f;
}

// ---------------- NCHW fp32 -> NHWC bf16 ----------------
__global__ __launch_bounds__(256) void k_transpose(const float* __restrict__ in,
                                                   unsigned short* __restrict__ out){
  __shared__ float tile[32][33];
  int b = blockIdx.z;
  int c0 = blockIdx.y*32;
  int p0 = blockIdx.x*32;
  int tx = threadIdx.x, ty = threadIdx.y;
  const float* src = in + (size_t)b*CDIM*HW;
  unsigned short* dst = out + (size_t)b*HW*CDIM;
  #pragma unroll
  for (int i=ty;i<32;i+=8) tile[i][tx] = src[(size_t)(c0+i)*HW + p0+tx];
  __syncthreads();
  #pragma unroll
  for (int i=ty;i<32;i+=8) dst[(size_t)(p0+i)*CDIM + c0+tx] = f2bf(tile[tx][i]);
}

// ---------------- weight packers: fragment-linear bf16 ----------------
__global__ void k_pack_w(const float* __restrict__ src, unsigned short* __restrict__ dst,
                         int ksn, int K, int total){
  for (int i=blockIdx.x*256+threadIdx.x; i<total; i+=gridDim.x*256){
    int r=i&7, l=(i>>3)&63, ks=(i>>9)%ksn, J=i/(ksn*512);
    int j=J*16+(l&15), k=ks*32+((l>>4)<<3)+r;
    dst[i]=f2bf(src[(size_t)j*K+k]);
  }
}
__global__ void k_pack_off(const float* __restrict__ src, unsigned short* __restrict__ dst){
  const int total=2*72*512;
  for (int i=blockIdx.x*256+threadIdx.x; i<total; i+=gridDim.x*256){
    int r=i&7, l=(i>>3)&63, ks=(i>>9)%72, J=i/(72*512);
    int oc=J*16+(l&15), k=ks*32+((l>>4)<<3)+r;
    int tap=k>>8, ch=k&255;
    float v = (oc<18) ? src[((size_t)(oc*256+ch)*3 + tap/3)*3 + (tap%3)] : 0.f;
    dst[i]=f2bf(v);
  }
}
// depthwise weights -> fp32 [branch][tap][ch]
__global__ void k_pack_dwt(const float* __restrict__ s0, const float* __restrict__ s1,
                           const float* __restrict__ s2, float* __restrict__ dst){
  int i = blockIdx.x*256+threadIdx.x;
  if (i < 3*9*256){
    int j=i/2304, rem=i%2304, k=rem/256, c=rem%256;
    const float* s = j==0?s0:(j==1?s1:s2);
    dst[i] = s[c*9+k];
  }
}

// ---------------- offset conv via MFMA: D[oc][pix] = Woff . T^T ----------------
template<int DIL>
__global__ __launch_bounds__(256) void k_offconv(const unsigned short* __restrict__ xtb,
    const unsigned short* __restrict__ wp, float* __restrict__ off){
  __shared__ float part[4*2*2*64*4];   // 16KB
  int t=threadIdx.x, l=t&63, wv=t>>6, q=l>>4;
  int p0=blockIdx.x*32;
  int b=p0>>14, prow=p0&(HW-1);
  int hh=prow>>7, w0=prow&(WDIM-1);
  const unsigned short* xb = xtb + (size_t)b*HW*CDIM;
  f32x4 acc[2][2];
  #pragma unroll
  for(int mi=0;mi<2;mi++)
    #pragma unroll
    for(int pi=0;pi<2;pi++) acc[mi][pi]=(f32x4){0.f,0.f,0.f,0.f};
  for(int i=0;i<18;i++){
    int ks = wv + 4*i;
    int k0 = ks*32;
    int tap = k0>>8;
    int ky = tap/3, kx = tap%3;
    int chb = (k0&255) + q*8;
    bf16x8 a0 = *(const bf16x8*)(wp + ((size_t)(0*72+ks)*64 + l)*8);
    bf16x8 a1 = *(const bf16x8*)(wp + ((size_t)(1*72+ks)*64 + l)*8);
    int y = hh + (ky-1)*DIL;
    bf16x8 bfr[2];
    #pragma unroll
    for(int pi=0;pi<2;pi++){
      int x = w0 + pi*16 + (l&15) + (kx-1)*DIL;
      bf16x8 v = {0,0,0,0,0,0,0,0};
      if((unsigned)y<HDIM && (unsigned)x<WDIM)
        v = *(const bf16x8*)(xb + ((size_t)y*WDIM + x)*CDIM + chb);
      bfr[pi]=v;
    }
    #pragma unroll
    for(int pi=0;pi<2;pi++){
      acc[0][pi]=__builtin_amdgcn_mfma_f32_16x16x32_bf16(a0,bfr[pi],acc[0][pi],0,0,0);
      acc[1][pi]=__builtin_amdgcn_mfma_f32_16x16x32_bf16(a1,bfr[pi],acc[1][pi],0,0,0);
    }
  }
  #pragma unroll
  for(int mi=0;mi<2;mi++)
    #pragma unroll
    for(int pi=0;pi<2;pi++){
      float* pp = &part[(((wv*2+mi)*2+pi)*64 + l)*4];
      pp[0]=acc[mi][pi].x; pp[1]=acc[mi][pi].y; pp[2]=acc[mi][pi].z; pp[3]=acc[mi][pi].w;
    }
  __syncthreads();
  if(wv==0){
    #pragma unroll
    for(int mi=0;mi<2;mi++)
      #pragma unroll
      for(int pi=0;pi<2;pi++)
        #pragma unroll
        for(int r=0;r<4;r++){
          int oc = mi*16 + q*4 + r;
          if(oc<18){
            float s=0.f;
            #pragma unroll
            for(int ww=0;ww<4;ww++) s += part[(((ww*2+mi)*2+pi)*64+l)*4 + r];
            off[(size_t)(p0 + pi*16 + (l&15))*54 + oc] = s;
          }
        }
  }
}

// ---------------- 1x1 conv via MFMA: acc[pix][oc] = conv_w . x^T + b ----------------
__global__ __launch_bounds__(256) void k_conv1x1(const unsigned short* __restrict__ xtb,
    const unsigned short* __restrict__ cwp, const float* __restrict__ cb,
    float* __restrict__ acc){
  __shared__ float sacc[32*260];
  int t=threadIdx.x, l=t&63, wv=t>>6, q=l>>4;
  size_t p0=(size_t)blockIdx.x*32;
  f32x4 c[4][2];
  #pragma unroll
  for(int ci=0;ci<4;ci++)
    #pragma unroll
    for(int pi=0;pi<2;pi++) c[ci][pi]=(f32x4){0.f,0.f,0.f,0.f};
  for(int ks=0;ks<8;ks++){
    bf16x8 bfr[2];
    #pragma unroll
    for(int pi=0;pi<2;pi++)
      bfr[pi] = *(const bf16x8*)(xtb + (p0 + pi*16 + (l&15))*CDIM + ks*32 + q*8);
    #pragma unroll
    for(int ci=0;ci<4;ci++){
      int J = wv*4+ci;
      bf16x8 a = *(const bf16x8*)(cwp + ((size_t)(J*8+ks)*64+l)*8);
      #pragma unroll
      for(int pi=0;pi<2;pi++)
        c[ci][pi]=__builtin_amdgcn_mfma_f32_16x16x32_bf16(a,bfr[pi],c[ci][pi],0,0,0);
    }
  }
  #pragma unroll
  for(int ci=0;ci<4;ci++){
    int ocb = (wv*4+ci)*16 + q*4;
    float4 bb = *(const float4*)&cb[ocb];
    #pragma unroll
    for(int pi=0;pi<2;pi++){
      int pix = pi*16+(l&15);
      sacc[pix*260 + ocb+0] = c[ci][pi].x + bb.x;
      sacc[pix*260 + ocb+1] = c[ci][pi].y + bb.y;
      sacc[pix*260 + ocb+2] = c[ci][pi].z + bb.z;
      sacc[pix*260 + ocb+3] = c[ci][pi].w + bb.w;
    }
  }
  __syncthreads();
  for(int i=0;i<32;i++) acc[(p0+i)*CDIM + t] = sacc[i*260 + t];
}

// ------- fused 3-branch deformable depthwise 3x3 + LN + GELU, acc += ... -------
// one pixel per wave; lane = (x-corner h=l>>5, channel octet c0=(l&31)*8)
// fp32 depthwise weights read from global (6.9KB, L1-resident); no LDS, no syncthreads.
__global__ __launch_bounds__(256) void k_deform3(const unsigned short* __restrict__ xtb,
    const float* __restrict__ offall, const float* __restrict__ wkt,
    const float* __restrict__ lw0, const float* __restrict__ lb0,
    const float* __restrict__ lw1, const float* __restrict__ lb1,
    const float* __restrict__ lw2, const float* __restrict__ lb2,
    float* __restrict__ acc){
  int t=threadIdx.x, l=t&63, wv=t>>6;
  // XCD swizzle: nwg=8192 (%8==0), 1024 contiguous blocks per XCD
  int bid = blockIdx.x;
  int swz = (bid&7)*1024 + (bid>>3);
  size_t gp = (size_t)swz*4 + wv;
  int b=(int)(gp>>14); int p=(int)(gp&(HW-1)); int hh=p>>7, ww=p&(WDIM-1);
  float voff = (l<54) ? offall[gp*54 + l] : 0.f;
  const unsigned short* xb = xtb + (size_t)b*HW*CDIM;
  const int h = l>>5;           // x-corner this half-wave owns
  const int c0 = (l&31)*8;      // channel octet
  float out4[4]={0.f,0.f,0.f,0.f};
  #pragma unroll 1
  for(int j=0;j<3;j++){
    const int DIL = (j==0)?1:((j==1)?9:12);
    float d8[8];
    #pragma unroll
    for(int e=0;e<8;e++) d8[e]=0.f;
    #pragma unroll 3
    for(int k=0;k<9;k++){
      float oy = __shfl(voff, j*18+2*k);
      float ox = __shfl(voff, j*18+2*k+1);
      float py = (float)(hh+(k/3-1)*DIL)+oy;
      float px = (float)(ww+(k%3-1)*DIL)+ox;
      float y0f=floorf(py), x0f=floorf(px);
      float fy=py-y0f, fx=px-x0f;
      int iy=(int)y0f, ix=(int)x0f;
      int xx = ix + h;
      float wx = h ? fx : 1.f-fx;
      bf16x8 r0={0,0,0,0,0,0,0,0}, r1={0,0,0,0,0,0,0,0};
      if((unsigned)xx < WDIM){
        if((unsigned)iy < HDIM)
          r0 = *(const bf16x8*)(xb + ((size_t)iy*WDIM + xx)*CDIM + c0);
        if((unsigned)(iy+1) < HDIM)
          r1 = *(const bf16x8*)(xb + ((size_t)(iy+1)*WDIM + xx)*CDIM + c0);
      }
      float w0 = wx*(1.f-fy), w1 = wx*fy;
      float4 wkA = *(const float4*)&wkt[(j*9+k)*256 + c0];
      float4 wkB = *(const float4*)&wkt[(j*9+k)*256 + c0 + 4];
      float wk8[8]={wkA.x,wkA.y,wkA.z,wkA.w,wkB.x,wkB.y,wkB.z,wkB.w};
      #pragma unroll
      for(int e=0;e<8;e++)
        d8[e] = fmaf(wk8[e],
                     fmaf(w1, bf2f((unsigned short)r1[e]), w0*bf2f((unsigned short)r0[e])),
                     d8[e]);
    }
    // combine x-corner halves (lanes l <-> l+32); both halves now identical
    #pragma unroll
    for(int e=0;e<8;e++) d8[e] += __shfl_xor(d8[e], 32);
    // LN stats (reduce within 32-lane half; halves identical)
    float s=0.f, sq=0.f;
    #pragma unroll
    for(int e=0;e<8;e++){ s+=d8[e]; sq+=d8[e]*d8[e]; }
    #pragma unroll
    for(int m=1;m<32;m<<=1){ s+=__shfl_xor(s,m); sq+=__shfl_xor(sq,m); }
    float u=s*(1.f/CDIM);
    float var=sq*(1.f/CDIM)-u*u;
    float rs=rsqrtf(var+1e-6f);
    // each half-wave finishes only its 4 channels
    float g0 = h ? d8[4] : d8[0];
    float g1 = h ? d8[5] : d8[1];
    float g2 = h ? d8[6] : d8[2];
    float g3 = h ? d8[7] : d8[3];
    const float* lw = j==0?lw0:(j==1?lw1:lw2);
    const float* lb = j==0?lb0:(j==1?lb1:lb2);
    int cb = c0 + 4*h;
    float4 wv4 = *(const float4*)&lw[cb];
    float4 bv4 = *(const float4*)&lb[cb];
    out4[0] += geluf(wv4.x*((g0-u)*rs)+bv4.x);
    out4[1] += geluf(wv4.y*((g1-u)*rs)+bv4.y);
    out4[2] += geluf(wv4.z*((g2-u)*rs)+bv4.z);
    out4[3] += geluf(wv4.w*((g3-u)*rs)+bv4.w);
  }
  float4* ap = (float4*)&acc[gp*CDIM + c0 + 4*h];
  float4 av = *ap;
  av.x+=out4[0]; av.y+=out4[1]; av.z+=out4[2]; av.w+=out4[3];
  *ap = av;
}

// ------- fused LN1 + MLP(256->512 gelu ->256, MFMA) + residual + LN2 + NCHW -------
__global__ __launch_bounds__(256) void k_mlp(const float* __restrict__ acc,
    const unsigned short* __restrict__ w1p, const float* __restrict__ b1,
    const unsigned short* __restrict__ w2p, const float* __restrict__ b2,
    const float* __restrict__ n1w, const float* __restrict__ n1b,
    const float* __restrict__ n2w, const float* __restrict__ n2b,
    float* __restrict__ dout){
  __shared__ unsigned short xbf[32*256];
  __shared__ unsigned short hbf[32*512];
  __shared__ float redS[4*32], redQ[4*32];
  int t=threadIdx.x, l=t&63, wv=t>>6, q=l>>4;
  size_t p0=(size_t)blockIdx.x*32;
  {
    int p=t>>3, i=t&7;
    const float* ar = acc + (p0+p)*CDIM + i*32;
    float v[32];
    float s=0.f, sq=0.f;
    #pragma unroll
    for(int j=0;j<32;j+=4){
      float4 x4 = *(const float4*)&ar[j];
      v[j]=x4.x; v[j+1]=x4.y; v[j+2]=x4.z; v[j+3]=x4.w;
      s += x4.x+x4.y+x4.z+x4.w;
      sq += x4.x*x4.x+x4.y*x4.y+x4.z*x4.z+x4.w*x4.w;
    }
    #pragma unroll
    for(int m=1;m<8;m<<=1){ s += __shfl_xor(s,m); sq += __shfl_xor(sq,m); }
    float u=s*(1.f/CDIM), var=sq*(1.f/CDIM)-u*u, rs=rsqrtf(var+1e-6f);
    #pragma unroll
    for(int g4=0; g4<4; ++g4){
      bf16x8 vec;
      #pragma unroll
      for(int e=0;e<8;e++){
        int c=i*32+g4*8+e;
        float y=(v[g4*8+e]-u)*rs*n1w[c]+n1b[c];
        vec[e]=(short)f2bf(y);
      }
      int g = i*4 + g4;
      *(bf16x8*)&xbf[p*256 + ((g ^ (p&7))<<3)] = vec;
    }
  }
  __syncthreads();
  f32x4 c1[8][2];
  #pragma unroll
  for(int ji=0;ji<8;ji++){ c1[ji][0]=(f32x4){0.f,0.f,0.f,0.f}; c1[ji][1]=(f32x4){0.f,0.f,0.f,0.f}; }
  for(int ks=0;ks<8;ks++){
    bf16x8 bx[2];
    #pragma unroll
    for(int pi=0;pi<2;pi++){
      int pix=pi*16+(l&15);
      int g=ks*4+q;
      bx[pi]=*(const bf16x8*)&xbf[pix*256 + ((g^(pix&7))<<3)];
    }
    #pragma unroll
    for(int ji=0;ji<8;ji++){
      bf16x8 a=*(const bf16x8*)(w1p + ((size_t)((wv*8+ji)*8+ks)*64+l)*8);
      c1[ji][0]=__builtin_amdgcn_mfma_f32_16x16x32_bf16(a,bx[0],c1[ji][0],0,0,0);
      c1[ji][1]=__builtin_amdgcn_mfma_f32_16x16x32_bf16(a,bx[1],c1[ji][1],0,0,0);
    }
  }
  #pragma unroll
  for(int ji=0;ji<8;ji++){
    int jb=(wv*8+ji)*16 + q*4;
    float4 bb=*(const float4*)&b1[jb];
    #pragma unroll
    for(int pi=0;pi<2;pi++){
      int pix=pi*16+(l&15);
      bf16x4 t4;
      t4[0]=(short)f2bf(geluf(c1[ji][pi].x+bb.x));
      t4[1]=(short)f2bf(geluf(c1[ji][pi].y+bb.y));
      t4[2]=(short)f2bf(geluf(c1[ji][pi].z+bb.z));
      t4[3]=(short)f2bf(geluf(c1[ji][pi].w+bb.w));
      int g=jb>>3;
      *(bf16x4*)&hbf[pix*512 + ((g^(pix&7))<<3) + (jb&7)] = t4;
    }
  }
  __syncthreads();
  f32x4 c2[4][2];
  #pragma unroll
  for(int ci=0;ci<4;ci++){ c2[ci][0]=(f32x4){0.f,0.f,0.f,0.f}; c2[ci][1]=(f32x4){0.f,0.f,0.f,0.f}; }
  for(int ks=0;ks<16;ks++){
    bf16x8 bh[2];
    #pragma unroll
    for(int pi=0;pi<2;pi++){
      int pix=pi*16+(l&15);
      int g=ks*4+q;
      bh[pi]=*(const bf16x8*)&hbf[pix*512 + ((g^(pix&7))<<3)];
    }
    #pragma unroll
    for(int ci=0;ci<4;ci++){
      bf16x8 a=*(const bf16x8*)(w2p + ((size_t)((wv*4+ci)*16+ks)*64+l)*8);
      c2[ci][0]=__builtin_amdgcn_mfma_f32_16x16x32_bf16(a,bh[0],c2[ci][0],0,0,0);
      c2[ci][1]=__builtin_amdgcn_mfma_f32_16x16x32_bf16(a,bh[1],c2[ci][1],0,0,0);
    }
  }
  float z[4][2][4];
  float sp[2]={0.f,0.f}, sqp[2]={0.f,0.f};
  #pragma unroll
  for(int ci=0;ci<4;ci++){
    int cb=(wv*4+ci)*16+q*4;
    float4 bb=*(const float4*)&b2[cb];
    int g=cb>>3;
    #pragma unroll
    for(int pi=0;pi<2;pi++){
      int pix=pi*16+(l&15);
      bf16x4 rr=*(const bf16x4*)&xbf[pix*256 + ((g^(pix&7))<<3) + (cb&7)];
      float z0=c2[ci][pi].x+bb.x+bf2f((unsigned short)rr[0]);
      float z1=c2[ci][pi].y+bb.y+bf2f((unsigned short)rr[1]);
      float z2=c2[ci][pi].z+bb.z+bf2f((unsigned short)rr[2]);
      float z3=c2[ci][pi].w+bb.w+bf2f((unsigned short)rr[3]);
      z[ci][pi][0]=z0; z[ci][pi][1]=z1; z[ci][pi][2]=z2; z[ci][pi][3]=z3;
      sp[pi]+=z0+z1+z2+z3;
      sqp[pi]+=z0*z0+z1*z1+z2*z2+z3*z3;
    }
  }
  #pragma unroll
  for(int m=16;m<64;m<<=1){
    sp[0]+=__shfl_xor(sp[0],m); sp[1]+=__shfl_xor(sp[1],m);
    sqp[0]+=__shfl_xor(sqp[0],m); sqp[1]+=__shfl_xor(sqp[1],m);
  }
  if(q==0){
    redS[wv*32 + (l&15)]=sp[0];  redS[wv*32 + 16 + (l&15)]=sp[1];
    redQ[wv*32 + (l&15)]=sqp[0]; redQ[wv*32 + 16 + (l&15)]=sqp[1];
  }
  __syncthreads();
  float u[2], rs[2];
  #pragma unroll
  for(int pi=0;pi<2;pi++){
    int pix=pi*16+(l&15);
    float S=redS[pix]+redS[32+pix]+redS[64+pix]+redS[96+pix];
    float Q=redQ[pix]+redQ[32+pix]+redQ[64+pix]+redQ[96+pix];
    u[pi]=S*(1.f/CDIM);
    rs[pi]=rsqrtf(Q*(1.f/CDIM)-u[pi]*u[pi]+1e-6f);
  }
  int bimg=(int)(p0>>14); int prow0=(int)(p0&(HW-1));
  #pragma unroll
  for(int ci=0;ci<4;ci++){
    int cb=(wv*4+ci)*16+q*4;
    float4 wv4=*(const float4*)&n2w[cb];
    float4 bv4=*(const float4*)&n2b[cb];
    #pragma unroll
    for(int pi=0;pi<2;pi++){
      int prow = prow0 + pi*16 + (l&15);
      dout[((size_t)(bimg*CDIM+cb+0))*HW + prow] = (z[ci][pi][0]-u[pi])*rs[pi]*wv4.x+bv4.x;
      dout[((size_t)(bimg*CDIM+cb+1))*HW + prow] = (z[ci][pi][1]-u[pi])*rs[pi]*wv4.y+bv4.y;
      dout[((size_t)(bimg*CDIM+cb+2))*HW + prow] = (z[ci][pi][2]-u[pi])*rs[pi]*wv4.z+bv4.z;
      dout[((size_t)(bimg*CDIM+cb+3))*HW + prow] = (z[ci][pi][3]-u[pi])*rs[pi]*wv4.w+bv4.w;
    }
  }
}

extern "C" void kernel_launch(void* const* d_in, const int* in_sizes, int n_in,
                              void* d_out, int out_size, void* d_ws, size_t ws_size,
                              hipStream_t stream){
  const float* x = (const float*)d_in[0];
  const float* off_w[3] = {(const float*)d_in[1],(const float*)d_in[5],(const float*)d_in[9]};
  const float* def_w[3] = {(const float*)d_in[2],(const float*)d_in[6],(const float*)d_in[10]};
  const float* bw[3]    = {(const float*)d_in[3],(const float*)d_in[7],(const float*)d_in[11]};
  const float* bbr[3]   = {(const float*)d_in[4],(const float*)d_in[8],(const float*)d_in[12]};
  const float* conv_w = (const float*)d_in[13];
  const float* conv_b = (const float*)d_in[14];
  const float* n1w = (const float*)d_in[15];
  const float* n1b = (const float*)d_in[16];
  const float* n2w = (const float*)d_in[17];
  const float* n2b = (const float*)d_in[18];
  const float* w1  = (const float*)d_in[19];
  const float* b1  = (const float*)d_in[20];
  const float* w2  = (const float*)d_in[21];
  const float* b2  = (const float*)d_in[22];

  unsigned short* xtb = (unsigned short*)d_ws;                       // NPIX*256 bf16
  float* acc  = (float*)(xtb + (size_t)NPIX*CDIM);                   // NPIX*256 f32
  float* offall = acc + (size_t)NPIX*CDIM;                           // NPIX*54 f32
  unsigned short* w1p  = (unsigned short*)(offall + (size_t)NPIX*54);// 131072
  unsigned short* w2p  = w1p + 131072;                               // 131072
  unsigned short* cwp  = w2p + 131072;                               // 65536
  unsigned short* wop0 = cwp + 65536;                                // 73728 each
  unsigned short* wop1 = wop0 + 73728;
  unsigned short* wop2 = wop1 + 73728;
  float* wkt = (float*)(wop2 + 73728);                               // 6912 f32

  k_transpose<<<dim3(HW/32, CDIM/32, BDIM), dim3(32,8), 0, stream>>>(x, xtb);
  k_pack_w<<<512, 256, 0, stream>>>(w1, w1p, 8, 256, 131072);
  k_pack_w<<<512, 256, 0, stream>>>(w2, w2p, 16, 512, 131072);
  k_pack_w<<<256, 256, 0, stream>>>(conv_w, cwp, 8, 256, 65536);
  k_pack_off<<<288, 256, 0, stream>>>(off_w[0], wop0);
  k_pack_off<<<288, 256, 0, stream>>>(off_w[1], wop1);
  k_pack_off<<<288, 256, 0, stream>>>(off_w[2], wop2);
  k_pack_dwt<<<27, 256, 0, stream>>>(def_w[0], def_w[1], def_w[2], wkt);
  k_offconv<1> <<<NPIX/32, 256, 0, stream>>>(xtb, wop0, offall + 0);
  k_offconv<9> <<<NPIX/32, 256, 0, stream>>>(xtb, wop1, offall + 18);
  k_offconv<12><<<NPIX/32, 256, 0, stream>>>(xtb, wop2, offall + 36);
  k_conv1x1<<<NPIX/32, 256, 0, stream>>>(xtb, cwp, conv_b, acc);
  k_deform3<<<NPIX/4, 256, 0, stream>>>(xtb, offall, wkt,
      bw[0], bbr[0], bw[1], bbr[1], bw[2], bbr[2], acc);
  k_mlp<<<NPIX/32, 256, 0, stream>>>(acc, w1p, b1, w2p, b2, n1w, n1b, n2w, n2b, (float*)d_out);
}